// Round 2
// baseline (355.574 us; speedup 1.0000x reference)
//
#include <hip/hip_runtime.h>
#include <hip/hip_bf16.h>

// GQA block for MI355X. bf16 MFMA 16x16x32, fp32 accumulation.
// Pipeline:
//   cvt X -> bf16 (Xb)
//   transpose+cvt [Wq|Wk|Wv] -> fused WqkvT [3072,2048] bf16 ; Wo -> Wot [2048,2048]
//   fused gemm (global_load_lds staging): Qb [4096,2048], Kb [4096,512], Vt [512,4096] (V transposed)
//   flash attention: 256-thr blocks (4 waves = 4 heads of one group), 32 q-rows/block,
//     2 blocks/CU for cross-block barrier overlap; async next-tile loads issued at
//     compute start (latency hidden under QK^T/softmax/PV); Ps XOR-swizzled.
//   gemm: out = Ab @ Wo + bo (fp32)

typedef __attribute__((ext_vector_type(8))) short short8;
typedef __attribute__((ext_vector_type(4))) short short4v;
typedef __attribute__((ext_vector_type(4))) float float4v;

#define C1F 0.12751743f   // (1/sqrt(128)) * log2(e)
#define B0F -16.0f        // fixed max offset in log2 units (scores bounded ~|8| log2 units)

#if defined(__has_builtin) && __has_builtin(__builtin_amdgcn_exp2f)
#define EXP2(x) __builtin_amdgcn_exp2f(x)
#else
#define EXP2(x) exp2f(x)
#endif

__device__ __forceinline__ short f2bf(float x) {
    __hip_bfloat16 h = __float2bfloat16(x);
    short s; __builtin_memcpy(&s, &h, sizeof(s)); return s;
}

__device__ __forceinline__ void gl16(const short* g, short* l) {
    __builtin_amdgcn_global_load_lds(
        (const __attribute__((address_space(1))) void*)g,
        (__attribute__((address_space(3))) void*)l, 16, 0, 0);
}

// ---------------- fp32 -> bf16 elementwise ----------------
__global__ __launch_bounds__(256) void cvt_bf16_kernel(const float* __restrict__ in,
                                                       short* __restrict__ out, int n) {
    int i = (blockIdx.x * 256 + threadIdx.x) * 4;
    if (i >= n) return;
    float4 v = *(const float4*)(in + i);
    short4v o;
    o[0] = f2bf(v.x); o[1] = f2bf(v.y); o[2] = f2bf(v.z); o[3] = f2bf(v.w);
    *(short4v*)(out + i) = o;
}

// ---------------- W[K,N] fp32 -> Wt[N,K] bf16 ----------------
__global__ __launch_bounds__(256) void transpose_cvt_kernel(const float* __restrict__ W,
                                                            short* __restrict__ Wt,
                                                            int K, int N) {
    __shared__ float tile[32][33];
    int n0 = blockIdx.x * 32, k0 = blockIdx.y * 32;
    int tx = threadIdx.x & 31, ty = threadIdx.x >> 5;
#pragma unroll
    for (int i = 0; i < 4; ++i) {
        int kk = ty + i * 8;
        tile[kk][tx] = W[(size_t)(k0 + kk) * N + n0 + tx];
    }
    __syncthreads();
#pragma unroll
    for (int i = 0; i < 4; ++i) {
        int nn = ty + i * 8;
        Wt[(size_t)(n0 + nn) * K + k0 + tx] = f2bf(tile[tx][nn]);
    }
}

// ---------------- GEMM (m97 pattern): C = A[M,K] @ Bt[N,K]^T + bias ----------------
// 128x128 tile, BK=32, 4 waves. global_load_lds width-16 staging.
// mode 0: fused QKV epilogue (Q->O0 [*,2048], K->O1 [*,512], V->O2 transposed [512,4096])
// mode 1: fp32 out Of [*,2048] + b0
__global__ __launch_bounds__(256) void gemm_dma_kernel(
    const short* __restrict__ A, const short* __restrict__ Bt,
    const float* __restrict__ b0, const float* __restrict__ b1, const float* __restrict__ b2,
    short* __restrict__ O0, short* __restrict__ O1, short* __restrict__ O2,
    float* __restrict__ Of, int K, int mode) {
    __shared__ short As[128 * 32];
    __shared__ short Bs[128 * 32];
    const int t = threadIdx.x, lane = t & 63, w = t >> 6;
    const int l15 = lane & 15, quad = lane >> 4;
    const int wm = (w & 1) * 64, wn = (w >> 1) * 64;
    const int m0 = blockIdx.y * 128, n0 = blockIdx.x * 128;
    const int r4 = lane >> 2, c8 = (lane & 3) * 8;
    const short* ga = A + (size_t)(m0 + w * 16 + r4) * K + c8;
    const short* gb = Bt + (size_t)(n0 + w * 16 + r4) * K + c8;
    short* lA = As + (w * 16) * 32;   // wave-uniform LDS base, dst = base + lane*16B
    short* lB = Bs + (w * 16) * 32;

    float4v acc[4][4] = {};

    for (int k0 = 0; k0 < K; k0 += 32) {
        gl16(ga + k0, lA);
        gl16(ga + (size_t)64 * K + k0, lA + 64 * 32);
        gl16(gb + k0, lB);
        gl16(gb + (size_t)64 * K + k0, lB + 64 * 32);
        __syncthreads();   // drains vmcnt -> staging visible
        short8 af[4], bfr[4];
#pragma unroll
        for (int i = 0; i < 4; ++i)
            af[i] = *(const short8*)(As + (wm + i * 16 + l15) * 32 + quad * 8);
#pragma unroll
        for (int j = 0; j < 4; ++j)
            bfr[j] = *(const short8*)(Bs + (wn + j * 16 + l15) * 32 + quad * 8);
#pragma unroll
        for (int i = 0; i < 4; ++i)
#pragma unroll
            for (int j = 0; j < 4; ++j)
                acc[i][j] = __builtin_amdgcn_mfma_f32_16x16x32_bf16(af[i], bfr[j], acc[i][j], 0, 0, 0);
        __syncthreads();   // all reads done before next staging overwrite
    }

#pragma unroll
    for (int i = 0; i < 4; ++i) {
#pragma unroll
        for (int j = 0; j < 4; ++j) {
            const int col = n0 + wn + j * 16 + l15;
            const int row0 = m0 + wm + i * 16 + quad * 4;
            if (mode == 1) {
                const float bc = b0[col];
#pragma unroll
                for (int r = 0; r < 4; ++r)
                    Of[(size_t)(row0 + r) * 2048 + col] = acc[i][j][r] + bc;
            } else if (col < 2048) {
                const float bc = b0[col];
#pragma unroll
                for (int r = 0; r < 4; ++r)
                    O0[(size_t)(row0 + r) * 2048 + col] = f2bf(acc[i][j][r] + bc);
            } else if (col < 2560) {
                const int c = col - 2048;
                const float bc = b1[c];
#pragma unroll
                for (int r = 0; r < 4; ++r)
                    O1[(size_t)(row0 + r) * 512 + c] = f2bf(acc[i][j][r] + bc);
            } else {
                const int c = col - 2560;
                const float bc = b2[c];
#pragma unroll
                for (int r = 0; r < 4; ++r)
                    O2[(size_t)c * 4096 + row0 + r] = f2bf(acc[i][j][r] + bc);
            }
        }
    }
}

// ---------------- Flash attention, fixed-max exp2 softmax ----------------
// grid (S/32, G, B), 256 threads = 4 waves. Wave w: head = g + 4*w (jnp.tile
// semantics: group = h % 4), q-rows = qt*32 .. +32 (shared by all 4 waves).
// K/V tile (64 keys) staged per block; 2 blocks/CU overlap each other's barriers.
// Next tile's global loads issued at compute start -> latency hidden under MFMA.
// Ps XOR-swizzled (32B on row bit 3) -> conflict-free b16 stores.
__global__ __launch_bounds__(256, 2) void flash_kernel(
    const short* __restrict__ Qb, const short* __restrict__ Kb,
    const short* __restrict__ Vt, const int* __restrict__ mask,
    short* __restrict__ Ab) {
    __shared__ short Ks[64 * 136];    // keys x d, stride pad 136
    __shared__ short Vs[128 * 72];    // d x keys, stride pad 72
    __shared__ short Ps[4 * 32 * 72]; // per-wave P slices (32 q-rows x 64 keys)
    __shared__ float mb[64];

    const int t = threadIdx.x;
    const int lane = t & 63, w = t >> 6;           // w in 0..3
    const int l15 = lane & 15, quad = lane >> 4;
    const int qt = blockIdx.x, g = blockIdx.y, b = blockIdx.z;
    const int h = g + 4 * w;
    const int q0 = qt * 32;

    // Q fragments: 2 m-frags x 4 k-steps
    short8 qf[2][4];
#pragma unroll
    for (int mi = 0; mi < 2; ++mi)
#pragma unroll
        for (int ks = 0; ks < 4; ++ks)
            qf[mi][ks] = *(const short8*)(Qb + (size_t)(b * 2048 + q0 + mi * 16 + l15) * 2048
                                          + h * 128 + ks * 32 + quad * 8);

    float4v o[2][8] = {};
    float rsum[2][4] = {};
    short* PsW = Ps + w * (32 * 72);
    const int psxr = ((l15 >> 3) & 1) << 4;   // read-side XOR (row bit3 = l15 bit3 for rows l15 and 16+l15)

    const int kR = t >> 4, kC = (t & 15) * 8;  // K stage: rows kR+{0,16,32,48}
    const int vR = t >> 3, vC = (t & 7) * 8;   // V stage: rows vR+{0,32,64,96}
    const short* kg = Kb + (size_t)(b * 2048 + kR) * 512 + g * 128 + kC;
    const short* vg = Vt + (size_t)(g * 128 + vR) * 4096 + (size_t)b * 2048 + vC;

    short8 kv[4], vv[4];
    float mv = 0.f;

#define LOADT(KB)                                                                  \
    do {                                                                           \
        kv[0] = *(const short8*)(kg + (size_t)(KB) * 512);                         \
        kv[1] = *(const short8*)(kg + (size_t)((KB) + 16) * 512);                  \
        kv[2] = *(const short8*)(kg + (size_t)((KB) + 32) * 512);                  \
        kv[3] = *(const short8*)(kg + (size_t)((KB) + 48) * 512);                  \
        vv[0] = *(const short8*)(vg + (KB));                                       \
        vv[1] = *(const short8*)(vg + (size_t)32 * 4096 + (KB));                   \
        vv[2] = *(const short8*)(vg + (size_t)64 * 4096 + (KB));                   \
        vv[3] = *(const short8*)(vg + (size_t)96 * 4096 + (KB));                   \
        if (t < 64) mv = mask[b * 2048 + (KB) + t] ? B0F : -1e30f;                 \
    } while (0)

    LOADT(0);

    for (int kt = 0; kt < 32; ++kt) {
        __syncthreads();   // all waves finished reads of previous tile
#pragma unroll
        for (int i = 0; i < 4; ++i)
            *(short8*)(Ks + (kR + i * 16) * 136 + kC) = kv[i];
#pragma unroll
        for (int i = 0; i < 4; ++i)
            *(short8*)(Vs + (vR + i * 32) * 72 + vC) = vv[i];
        if (t < 64) mb[t] = mv;
        __syncthreads();   // staging visible

        if (kt + 1 < 32) LOADT((kt + 1) * 64);   // async: latency hides under compute

        // S = Q @ K^T (raw dot; scale folded into exp2)
        float4v s[2][4] = {};
        __builtin_amdgcn_s_setprio(1);
#pragma unroll
        for (int ks = 0; ks < 4; ++ks)
#pragma unroll
            for (int j = 0; j < 4; ++j) {
                short8 bk = *(const short8*)(Ks + (j * 16 + l15) * 136 + ks * 32 + quad * 8);
                s[0][j] = __builtin_amdgcn_mfma_f32_16x16x32_bf16(qf[0][ks], bk, s[0][j], 0, 0, 0);
                s[1][j] = __builtin_amdgcn_mfma_f32_16x16x32_bf16(qf[1][ks], bk, s[1][j], 0, 0, 0);
            }
        __builtin_amdgcn_s_setprio(0);
        // p = 2^(s*C1 + mb[col])   (mb = B0F or -1e30); accumulate row sums linearly
#pragma unroll
        for (int mi = 0; mi < 2; ++mi)
#pragma unroll
            for (int j = 0; j < 4; ++j) {
                const float mbias = mb[j * 16 + l15];
#pragma unroll
                for (int r = 0; r < 4; ++r) {
                    float p = EXP2(fmaf(s[mi][j][r], C1F, mbias));
                    rsum[mi][r] += p;
                    const int row = mi * 16 + quad * 4 + r;
                    PsW[row * 72 + ((j * 16 + l15) ^ (((row >> 3) & 1) << 4))] = f2bf(p);
                }
            }
        // O += P @ V (P round-trips LDS per-wave; no barrier needed)
        __builtin_amdgcn_s_setprio(1);
#pragma unroll
        for (int ks2 = 0; ks2 < 2; ++ks2) {
            short8 pa0 = *(const short8*)(PsW + l15 * 72 + ((ks2 * 32 + quad * 8) ^ psxr));
            short8 pa1 = *(const short8*)(PsW + (16 + l15) * 72 + ((ks2 * 32 + quad * 8) ^ psxr));
#pragma unroll
            for (int jj = 0; jj < 8; ++jj) {
                short8 bv = *(const short8*)(Vs + (jj * 16 + l15) * 72 + ks2 * 32 + quad * 8);
                o[0][jj] = __builtin_amdgcn_mfma_f32_16x16x32_bf16(pa0, bv, o[0][jj], 0, 0, 0);
                o[1][jj] = __builtin_amdgcn_mfma_f32_16x16x32_bf16(pa1, bv, o[1][jj], 0, 0, 0);
            }
        }
        __builtin_amdgcn_s_setprio(0);
    }
#undef LOADT

    // normalize: reduce rsum across the 16 l15 lanes (once), then store
    float rinv[2][4];
#pragma unroll
    for (int mi = 0; mi < 2; ++mi)
#pragma unroll
        for (int r = 0; r < 4; ++r) {
            float v = rsum[mi][r];
            v += __shfl_xor(v, 1, 64); v += __shfl_xor(v, 2, 64);
            v += __shfl_xor(v, 4, 64); v += __shfl_xor(v, 8, 64);
            rinv[mi][r] = (v > 0.f) ? 1.f / v : 0.f;
        }
    const size_t ob = (size_t)(b * 2048 + q0) * 2048 + h * 128;
#pragma unroll
    for (int mi = 0; mi < 2; ++mi)
#pragma unroll
        for (int jj = 0; jj < 8; ++jj)
#pragma unroll
            for (int r = 0; r < 4; ++r)
                Ab[ob + (size_t)(mi * 16 + quad * 4 + r) * 2048 + jj * 16 + l15] =
                    f2bf(o[mi][jj][r] * rinv[mi][r]);
}

extern "C" void kernel_launch(void* const* d_in, const int* in_sizes, int n_in,
                              void* d_out, int out_size, void* d_ws, size_t ws_size,
                              hipStream_t stream) {
    (void)in_sizes; (void)n_in; (void)out_size; (void)ws_size;
    const float* X  = (const float*)d_in[0];
    const int* mask = (const int*)d_in[1];
    const float* Wq = (const float*)d_in[2];
    const float* bq = (const float*)d_in[3];
    const float* Wk = (const float*)d_in[4];
    const float* bk = (const float*)d_in[5];
    const float* Wv = (const float*)d_in[6];
    const float* bv = (const float*)d_in[7];
    const float* Wo = (const float*)d_in[8];
    const float* bo = (const float*)d_in[9];
    float* out = (float*)d_out;

    char* ws = (char*)d_ws;
    short* Xb     = (short*)(ws + 0);          // 16,777,216 B (reused as Ab)
    short* WqkvT  = (short*)(ws + 16777216);   // 12,582,912 B [3072,2048]
    short* Wot    = (short*)(ws + 29360128);   //  8,388,608 B
    short* Qb     = (short*)(ws + 37748736);   // 16,777,216 B
    short* Kb     = (short*)(ws + 54525952);   //  4,194,304 B
    short* Vt     = (short*)(ws + 58720256);   //  4,194,304 B
    short* Ab     = Xb;

    const int M = 4096, HID = 2048, KV = 512;

    cvt_bf16_kernel<<<8192, 256, 0, stream>>>(X, Xb, M * HID);
    transpose_cvt_kernel<<<dim3(64, 64), 256, 0, stream>>>(Wq, WqkvT, HID, HID);
    transpose_cvt_kernel<<<dim3(16, 64), 256, 0, stream>>>(Wk, WqkvT + (size_t)2048 * 2048, HID, KV);
    transpose_cvt_kernel<<<dim3(16, 64), 256, 0, stream>>>(Wv, WqkvT + (size_t)2560 * 2048, HID, KV);
    transpose_cvt_kernel<<<dim3(64, 64), 256, 0, stream>>>(Wo, Wot, HID, HID);

    // fused Q|K|V projection: N = 3072
    gemm_dma_kernel<<<dim3(24, 32), 256, 0, stream>>>(
        Xb, WqkvT, bq, bk, bv, Qb, Kb, Vt, nullptr, HID, 0);

    flash_kernel<<<dim3(64, 4, 2), 256, 0, stream>>>(Qb, Kb, Vt, mask, Ab);

    gemm_dma_kernel<<<dim3(16, 32), 256, 0, stream>>>(
        Ab, Wot, bo, nullptr, nullptr, nullptr, nullptr, nullptr, out, HID, 1);
}

// Round 3
// 343.352 us; speedup vs baseline: 1.0356x; 1.0356x over previous
//
#include <hip/hip_runtime.h>
#include <hip/hip_bf16.h>

// GQA block for MI355X. bf16 MFMA, fp32 accumulation.
// Pipeline:
//   cvt X -> bf16 (Xb)
//   transpose+cvt [Wq|Wk|Wv] -> fused WqkvT [3072,2048] bf16 ; Wo -> Wot [2048,2048]
//   fused gemm (global_load_lds staging): Qb [4096,2048], Kb [4096,512], Vt [512,4096]
//     (V transposed AND token-permuted: within each 16-token group, token index bits 2<->3
//      swapped, so flash's PV contraction k-slot order matches the in-register P layout)
//   flash attention (32x32x16 MFMA): 256-thr blocks (4 waves = 4 heads of one group),
//     32 q-rows/block; swapped QK^T (mfma(K,Q)) puts a full 32-key P-slice per lane ->
//     softmax fully in-register, NO P LDS round-trip; K/V LDS double-buffered (1 barrier
//     per tile); 2-tile-deep register prefetch; mask via wave-uniform ballot bits.
//   gemm: out = Ab @ Wo + bo (fp32)

typedef __attribute__((ext_vector_type(8))) short short8;
typedef __attribute__((ext_vector_type(4))) short short4v;
typedef __attribute__((ext_vector_type(4))) float float4v;
typedef __attribute__((ext_vector_type(16))) float float16v;

#define C1F 0.12751743f   // (1/sqrt(128)) * log2(e)
#define B0F -16.0f        // fixed max offset in log2 units (scores bounded ~|8| log2 units)

#if defined(__has_builtin) && __has_builtin(__builtin_amdgcn_exp2f)
#define EXP2(x) __builtin_amdgcn_exp2f(x)
#else
#define EXP2(x) exp2f(x)
#endif

__device__ __forceinline__ short f2bf(float x) {
    __hip_bfloat16 h = __float2bfloat16(x);
    short s; __builtin_memcpy(&s, &h, sizeof(s)); return s;
}

__device__ __forceinline__ void gl16(const short* g, short* l) {
    __builtin_amdgcn_global_load_lds(
        (const __attribute__((address_space(1))) void*)g,
        (__attribute__((address_space(3))) void*)l, 16, 0, 0);
}

// ---------------- fp32 -> bf16 elementwise ----------------
__global__ __launch_bounds__(256) void cvt_bf16_kernel(const float* __restrict__ in,
                                                       short* __restrict__ out, int n) {
    int i = (blockIdx.x * 256 + threadIdx.x) * 4;
    if (i >= n) return;
    float4 v = *(const float4*)(in + i);
    short4v o;
    o[0] = f2bf(v.x); o[1] = f2bf(v.y); o[2] = f2bf(v.z); o[3] = f2bf(v.w);
    *(short4v*)(out + i) = o;
}

// ---------------- W[K,N] fp32 -> Wt[N,K] bf16 ----------------
__global__ __launch_bounds__(256) void transpose_cvt_kernel(const float* __restrict__ W,
                                                            short* __restrict__ Wt,
                                                            int K, int N) {
    __shared__ float tile[32][33];
    int n0 = blockIdx.x * 32, k0 = blockIdx.y * 32;
    int tx = threadIdx.x & 31, ty = threadIdx.x >> 5;
#pragma unroll
    for (int i = 0; i < 4; ++i) {
        int kk = ty + i * 8;
        tile[kk][tx] = W[(size_t)(k0 + kk) * N + n0 + tx];
    }
    __syncthreads();
#pragma unroll
    for (int i = 0; i < 4; ++i) {
        int nn = ty + i * 8;
        Wt[(size_t)(n0 + nn) * K + k0 + tx] = f2bf(tile[tx][nn]);
    }
}

// ---------------- GEMM (m97 pattern): C = A[M,K] @ Bt[N,K]^T + bias ----------------
// 128x128 tile, BK=32, 4 waves. global_load_lds width-16 staging.
// mode 0: fused QKV epilogue (Q->O0 [*,2048], K->O1 [*,512],
//         V->O2 transposed [512,4096] with within-16 token permutation bits2<->3)
// mode 1: fp32 out Of [*,2048] + b0
__global__ __launch_bounds__(256) void gemm_dma_kernel(
    const short* __restrict__ A, const short* __restrict__ Bt,
    const float* __restrict__ b0, const float* __restrict__ b1, const float* __restrict__ b2,
    short* __restrict__ O0, short* __restrict__ O1, short* __restrict__ O2,
    float* __restrict__ Of, int K, int mode) {
    __shared__ short As[128 * 32];
    __shared__ short Bs[128 * 32];
    const int t = threadIdx.x, lane = t & 63, w = t >> 6;
    const int l15 = lane & 15, quad = lane >> 4;
    const int wm = (w & 1) * 64, wn = (w >> 1) * 64;
    const int m0 = blockIdx.y * 128, n0 = blockIdx.x * 128;
    const int r4 = lane >> 2, c8 = (lane & 3) * 8;
    const short* ga = A + (size_t)(m0 + w * 16 + r4) * K + c8;
    const short* gb = Bt + (size_t)(n0 + w * 16 + r4) * K + c8;
    short* lA = As + (w * 16) * 32;   // wave-uniform LDS base, dst = base + lane*16B
    short* lB = Bs + (w * 16) * 32;

    float4v acc[4][4] = {};

    for (int k0 = 0; k0 < K; k0 += 32) {
        gl16(ga + k0, lA);
        gl16(ga + (size_t)64 * K + k0, lA + 64 * 32);
        gl16(gb + k0, lB);
        gl16(gb + (size_t)64 * K + k0, lB + 64 * 32);
        __syncthreads();   // drains vmcnt -> staging visible
        short8 af[4], bfr[4];
#pragma unroll
        for (int i = 0; i < 4; ++i)
            af[i] = *(const short8*)(As + (wm + i * 16 + l15) * 32 + quad * 8);
#pragma unroll
        for (int j = 0; j < 4; ++j)
            bfr[j] = *(const short8*)(Bs + (wn + j * 16 + l15) * 32 + quad * 8);
#pragma unroll
        for (int i = 0; i < 4; ++i)
#pragma unroll
            for (int j = 0; j < 4; ++j)
                acc[i][j] = __builtin_amdgcn_mfma_f32_16x16x32_bf16(af[i], bfr[j], acc[i][j], 0, 0, 0);
        __syncthreads();   // all reads done before next staging overwrite
    }

#pragma unroll
    for (int i = 0; i < 4; ++i) {
#pragma unroll
        for (int j = 0; j < 4; ++j) {
            const int col = n0 + wn + j * 16 + l15;
            const int row0 = m0 + wm + i * 16 + quad * 4;
            if (mode == 1) {
                const float bc = b0[col];
#pragma unroll
                for (int r = 0; r < 4; ++r)
                    Of[(size_t)(row0 + r) * 2048 + col] = acc[i][j][r] + bc;
            } else if (col < 2048) {
                const float bc = b0[col];
#pragma unroll
                for (int r = 0; r < 4; ++r)
                    O0[(size_t)(row0 + r) * 2048 + col] = f2bf(acc[i][j][r] + bc);
            } else if (col < 2560) {
                const int c = col - 2048;
                const float bc = b1[c];
#pragma unroll
                for (int r = 0; r < 4; ++r)
                    O1[(size_t)(row0 + r) * 512 + c] = f2bf(acc[i][j][r] + bc);
            } else {
                const int c = col - 2560;
                const float bc = b2[c];
                // token permutation for flash PV slot order: swap bits 2<->3 of the
                // within-16 token index (quad*4+r -> qsw*4+r)
                const int qsw = ((quad & 1) << 1) | (quad >> 1);
                const int prow = m0 + wm + i * 16 + qsw * 4;
#pragma unroll
                for (int r = 0; r < 4; ++r)
                    O2[(size_t)c * 4096 + prow + r] = f2bf(acc[i][j][r] + bc);
            }
        }
    }
}

// ---------------- Flash attention, 32x32 MFMA, in-register softmax ----------------
// grid (S/32, G, B), 256 threads = 4 waves. Wave w: head = g + 4*w (jnp.tile
// semantics: group = h % 4), q-rows = qt*32 .. +32 (shared by all 4 waves).
// Swapped QK^T: st = mfma(Kfrag, Qfrag) -> st[reg] = S[key, q=lane&31] with
// key = (reg&3)+8*(reg>>2)+4*(lane>>5) (+32 for st1). Softmax in-register.
// PV A-frag: straight bf16 pack of st regs; k-slot order matches V because Vt
// was token-permuted (bits 2<->3) at the QKV gemm epilogue.
// K/V double-buffered in LDS: ONE barrier per tile; loads prefetched 2 tiles deep.
__global__ __launch_bounds__(256, 2) void flash_kernel(
    const short* __restrict__ Qb, const short* __restrict__ Kb,
    const short* __restrict__ Vt, const int* __restrict__ mask,
    short* __restrict__ Ab) {
    __shared__ short Ks[2][64 * 136];   // keys x d, stride pad 136
    __shared__ short Vs[2][128 * 72];   // d x key-slot, stride pad 72

    const int t = threadIdx.x;
    const int lane = t & 63, w = t >> 6;            // w in 0..3
    const int l31 = lane & 31, hi = lane >> 5;
    const int qt = blockIdx.x, g = blockIdx.y, b = blockIdx.z;
    const int h = g + 4 * w;
    const int q0 = qt * 32;

    // Q fragments (B-operand of 32x32x16): lane: q-row = l31, d = dd*16 + hi*8 + j
    short8 qf[8];
#pragma unroll
    for (int dd = 0; dd < 8; ++dd)
        qf[dd] = *(const short8*)(Qb + (size_t)(b * 2048 + q0 + l31) * 2048
                                  + h * 128 + dd * 16 + hi * 8);

    float16v o[4] = {};
    float rsum = 0.f;

    const int kR = t >> 4, kC = (t & 15) * 8;  // K stage: rows kR+{0,16,32,48}
    const int vR = t >> 3, vC = (t & 7) * 8;   // V stage: rows vR+{0,32,64,96}
    const short* kg = Kb + (size_t)(b * 2048 + kR) * 512 + g * 128 + kC;
    const short* vg = Vt + (size_t)(g * 128 + vR) * 4096 + (size_t)b * 2048 + vC;

    short8 kv[4], vv[4];
    int mvr = 1;

#define LOADT(KB)                                                                  \
    do {                                                                           \
        kv[0] = *(const short8*)(kg + (size_t)(KB) * 512);                         \
        kv[1] = *(const short8*)(kg + (size_t)((KB) + 16) * 512);                  \
        kv[2] = *(const short8*)(kg + (size_t)((KB) + 32) * 512);                  \
        kv[3] = *(const short8*)(kg + (size_t)((KB) + 48) * 512);                  \
        vv[0] = *(const short8*)(vg + (KB));                                       \
        vv[1] = *(const short8*)(vg + (size_t)32 * 4096 + (KB));                   \
        vv[2] = *(const short8*)(vg + (size_t)64 * 4096 + (KB));                   \
        vv[3] = *(const short8*)(vg + (size_t)96 * 4096 + (KB));                   \
        mvr = mask[b * 2048 + (KB) + lane];                                        \
    } while (0)

#define STAGE(BUF)                                                                 \
    do {                                                                           \
        _Pragma("unroll")                                                          \
        for (int i_ = 0; i_ < 4; ++i_)                                             \
            *(short8*)(&Ks[BUF][(kR + i_ * 16) * 136 + kC]) = kv[i_];              \
        _Pragma("unroll")                                                          \
        for (int i_ = 0; i_ < 4; ++i_)                                             \
            *(short8*)(&Vs[BUF][(vR + i_ * 32) * 72 + vC]) = vv[i_];               \
    } while (0)

    LOADT(0);
    STAGE(0);
    unsigned long long bits = __ballot(mvr != 0);
    LOADT(64);
    __syncthreads();   // buf0 visible

    int cur = 0;
    unsigned long long bits_next = bits;

    for (int kt = 0; kt < 32; ++kt) {
        if (kt + 1 < 32) {
            STAGE(cur ^ 1);                       // tile kt+1 (safe: buf^1 last read in kt-1)
            bits_next = __ballot(mvr != 0);       // tile kt+1 mask bits
            if (kt + 2 < 32) LOADT((kt + 2) * 64);// prefetch 2 tiles ahead
        }
        const short* Ksb = &Ks[cur][0];
        const short* Vsb = &Vs[cur][0];

        // S^T = K @ Q^T : st[reg] = S[key, q=l31]
        float16v st0 = {}, st1 = {};
        __builtin_amdgcn_s_setprio(1);
#pragma unroll
        for (int dd = 0; dd < 8; ++dd) {
            short8 kf0 = *(const short8*)(Ksb + l31 * 136 + dd * 16 + hi * 8);
            short8 kf1 = *(const short8*)(Ksb + (32 + l31) * 136 + dd * 16 + hi * 8);
            st0 = __builtin_amdgcn_mfma_f32_32x32x16_bf16(kf0, qf[dd], st0, 0, 0, 0);
            st1 = __builtin_amdgcn_mfma_f32_32x32x16_bf16(kf1, qf[dd], st1, 0, 0, 0);
        }
        __builtin_amdgcn_s_setprio(0);

        // softmax in-register: p = 2^(s*C1 + B0F), zero masked keys
        const unsigned int mlo = ((unsigned int)bits) >> (4 * hi);
        const unsigned int mhi = ((unsigned int)(bits >> 32)) >> (4 * hi);
#pragma unroll
        for (int e = 0; e < 16; ++e) {
            const int koff = (e & 3) + 8 * (e >> 2);
            float p0 = EXP2(fmaf(st0[e], C1F, B0F));
            float p1 = EXP2(fmaf(st1[e], C1F, B0F));
            p0 = ((mlo >> koff) & 1) ? p0 : 0.f;
            p1 = ((mhi >> koff) & 1) ? p1 : 0.f;
            rsum += p0 + p1;
            st0[e] = p0; st1[e] = p1;
        }

        // O += P @ V: A-frag = straight pack of st regs (V token-permuted to match)
        __builtin_amdgcn_s_setprio(1);
#pragma unroll
        for (int cc = 0; cc < 4; ++cc) {
            short8 pa;
#pragma unroll
            for (int e = 0; e < 8; ++e) {
                const float pv_ = (cc & 2) ? st1[(cc & 1) * 8 + e] : st0[(cc & 1) * 8 + e];
                pa[e] = f2bf(pv_);
            }
#pragma unroll
            for (int db = 0; db < 4; ++db) {
                short8 vb = *(const short8*)(Vsb + (db * 32 + l31) * 72 + cc * 16 + hi * 8);
                o[db] = __builtin_amdgcn_mfma_f32_32x32x16_bf16(pa, vb, o[db], 0, 0, 0);
            }
        }
        __builtin_amdgcn_s_setprio(0);

        __syncthreads();   // all waves done reading buf[cur]; kt+1 staging complete
        bits = bits_next;
        cur ^= 1;
    }
#undef LOADT
#undef STAGE

    // rsum: lane holds sum over its 32 keys for q=l31; partner (lane^32) has the rest
    rsum += __shfl_xor(rsum, 32, 64);
    const float rinv = (rsum > 0.f) ? 1.f / rsum : 0.f;
    // redistribute: store-time lane needs rinv of q-rows (reg&3)+8*(reg>>2)+4*hi
    float rq[16];
#pragma unroll
    for (int e = 0; e < 16; ++e) {
        const int koff = (e & 3) + 8 * (e >> 2);
        rq[e] = __shfl(rinv, koff + 4 * hi, 64);
    }
    const size_t ob = (size_t)(b * 2048 + q0) * 2048 + h * 128;
#pragma unroll
    for (int db = 0; db < 4; ++db)
#pragma unroll
        for (int e = 0; e < 16; ++e) {
            const int koff = (e & 3) + 8 * (e >> 2);
            Ab[ob + (size_t)(koff + 4 * hi) * 2048 + db * 32 + l31] =
                f2bf(o[db][e] * rq[e]);
        }
}

extern "C" void kernel_launch(void* const* d_in, const int* in_sizes, int n_in,
                              void* d_out, int out_size, void* d_ws, size_t ws_size,
                              hipStream_t stream) {
    (void)in_sizes; (void)n_in; (void)out_size; (void)ws_size;
    const float* X  = (const float*)d_in[0];
    const int* mask = (const int*)d_in[1];
    const float* Wq = (const float*)d_in[2];
    const float* bq = (const float*)d_in[3];
    const float* Wk = (const float*)d_in[4];
    const float* bk = (const float*)d_in[5];
    const float* Wv = (const float*)d_in[6];
    const float* bv = (const float*)d_in[7];
    const float* Wo = (const float*)d_in[8];
    const float* bo = (const float*)d_in[9];
    float* out = (float*)d_out;

    char* ws = (char*)d_ws;
    short* Xb     = (short*)(ws + 0);          // 16,777,216 B (reused as Ab)
    short* WqkvT  = (short*)(ws + 16777216);   // 12,582,912 B [3072,2048]
    short* Wot    = (short*)(ws + 29360128);   //  8,388,608 B
    short* Qb     = (short*)(ws + 37748736);   // 16,777,216 B
    short* Kb     = (short*)(ws + 54525952);   //  4,194,304 B
    short* Vt     = (short*)(ws + 58720256);   //  4,194,304 B
    short* Ab     = Xb;

    const int M = 4096, HID = 2048, KV = 512;

    cvt_bf16_kernel<<<8192, 256, 0, stream>>>(X, Xb, M * HID);
    transpose_cvt_kernel<<<dim3(64, 64), 256, 0, stream>>>(Wq, WqkvT, HID, HID);
    transpose_cvt_kernel<<<dim3(16, 64), 256, 0, stream>>>(Wk, WqkvT + (size_t)2048 * 2048, HID, KV);
    transpose_cvt_kernel<<<dim3(16, 64), 256, 0, stream>>>(Wv, WqkvT + (size_t)2560 * 2048, HID, KV);
    transpose_cvt_kernel<<<dim3(64, 64), 256, 0, stream>>>(Wo, Wot, HID, HID);

    // fused Q|K|V projection: N = 3072
    gemm_dma_kernel<<<dim3(24, 32), 256, 0, stream>>>(
        Xb, WqkvT, bq, bk, bv, Qb, Kb, Vt, nullptr, HID, 0);

    flash_kernel<<<dim3(64, 4, 2), 256, 0, stream>>>(Qb, Kb, Vt, mask, Ab);

    gemm_dma_kernel<<<dim3(16, 32), 256, 0, stream>>>(
        Ab, Wot, bo, nullptr, nullptr, nullptr, nullptr, nullptr, out, HID, 1);
}

// Round 4
// 333.082 us; speedup vs baseline: 1.0675x; 1.0308x over previous
//
#include <hip/hip_runtime.h>
#include <hip/hip_bf16.h>

// GQA block for MI355X. bf16 MFMA, fp32 accumulation.
// Pipeline:
//   cvt X -> bf16 (Xb)
//   transpose_all: [Wq|Wk|Wv] -> fused WqkvT [3072,2048] bf16 ; Wo -> Wot (one launch)
//   fused gemm (global_load_lds staging): Qb [4096,2048], Kb [4096,512], Vt [512,4096]
//     (V transposed AND token-permuted: within each 16-token group, token index bits 2<->3
//      swapped, so flash's PV contraction k-slot order matches the in-register P layout)
//   flash attention (32x32x16 MFMA): 256-thr blocks (4 waves = 4 heads of one group),
//     32 q-rows/block; swapped QK^T (mfma(K,Q)) puts a full 32-key P-slice per lane ->
//     softmax fully in-register; K/V LDS double-buffered (1 barrier per tile);
//     mask fast-path (wave-uniform skip of per-key test); softmax(st1) overlapped
//     under PV(st0) MFMAs (intra-tile half pipeline).
//   gemm: out = Ab @ Wo + bo (fp32)

typedef __attribute__((ext_vector_type(8))) short short8;
typedef __attribute__((ext_vector_type(4))) short short4v;
typedef __attribute__((ext_vector_type(4))) float float4v;
typedef __attribute__((ext_vector_type(16))) float float16v;

#define C1F 0.12751743f   // (1/sqrt(128)) * log2(e)
#define B0F -16.0f        // fixed max offset in log2 units (scores bounded ~|8| log2 units)

#if defined(__has_builtin) && __has_builtin(__builtin_amdgcn_exp2f)
#define EXP2(x) __builtin_amdgcn_exp2f(x)
#else
#define EXP2(x) exp2f(x)
#endif

__device__ __forceinline__ short f2bf(float x) {
    __hip_bfloat16 h = __float2bfloat16(x);
    short s; __builtin_memcpy(&s, &h, sizeof(s)); return s;
}

__device__ __forceinline__ void gl16(const short* g, short* l) {
    __builtin_amdgcn_global_load_lds(
        (const __attribute__((address_space(1))) void*)g,
        (__attribute__((address_space(3))) void*)l, 16, 0, 0);
}

// ---------------- fp32 -> bf16 elementwise ----------------
__global__ __launch_bounds__(256) void cvt_bf16_kernel(const float* __restrict__ in,
                                                       short* __restrict__ out, int n) {
    int i = (blockIdx.x * 256 + threadIdx.x) * 4;
    if (i >= n) return;
    float4 v = *(const float4*)(in + i);
    short4v o;
    o[0] = f2bf(v.x); o[1] = f2bf(v.y); o[2] = f2bf(v.z); o[3] = f2bf(v.w);
    *(short4v*)(out + i) = o;
}

// ---------------- all weight transposes in ONE launch ----------------
// blockIdx.x: [0,64) Wq -> WqkvT ; [64,80) Wk -> WqkvT+2048*2048 ;
//             [80,96) Wv -> WqkvT+2560*2048 ; [96,160) Wo -> Wot. K=2048 always.
__global__ __launch_bounds__(256) void transpose_all_kernel(
    const float* __restrict__ Wq, const float* __restrict__ Wk,
    const float* __restrict__ Wv, const float* __restrict__ Wo,
    short* __restrict__ WqkvT, short* __restrict__ Wot) {
    __shared__ float tile[32][33];
    int bx = blockIdx.x;
    const float* W; short* Wt; int N;
    if (bx < 64)      { W = Wq; Wt = WqkvT;                      N = 2048; }
    else if (bx < 80) { W = Wk; Wt = WqkvT + (size_t)2048 * 2048; N = 512; bx -= 64; }
    else if (bx < 96) { W = Wv; Wt = WqkvT + (size_t)2560 * 2048; N = 512; bx -= 80; }
    else              { W = Wo; Wt = Wot;                        N = 2048; bx -= 96; }
    const int K = 2048;
    int n0 = bx * 32, k0 = blockIdx.y * 32;
    int tx = threadIdx.x & 31, ty = threadIdx.x >> 5;
#pragma unroll
    for (int i = 0; i < 4; ++i) {
        int kk = ty + i * 8;
        tile[kk][tx] = W[(size_t)(k0 + kk) * N + n0 + tx];
    }
    __syncthreads();
#pragma unroll
    for (int i = 0; i < 4; ++i) {
        int nn = ty + i * 8;
        Wt[(size_t)(n0 + nn) * K + k0 + tx] = f2bf(tile[tx][nn]);
    }
}

// ---------------- GEMM (m97 pattern): C = A[M,K] @ Bt[N,K]^T + bias ----------------
// 128x128 tile, BK=32, 4 waves. global_load_lds width-16 staging.
// mode 0: fused QKV epilogue (Q->O0 [*,2048], K->O1 [*,512],
//         V->O2 transposed [512,4096] with within-16 token permutation bits2<->3)
// mode 1: fp32 out Of [*,2048] + b0
__global__ __launch_bounds__(256) void gemm_dma_kernel(
    const short* __restrict__ A, const short* __restrict__ Bt,
    const float* __restrict__ b0, const float* __restrict__ b1, const float* __restrict__ b2,
    short* __restrict__ O0, short* __restrict__ O1, short* __restrict__ O2,
    float* __restrict__ Of, int K, int mode) {
    __shared__ short As[128 * 32];
    __shared__ short Bs[128 * 32];
    const int t = threadIdx.x, lane = t & 63, w = t >> 6;
    const int l15 = lane & 15, quad = lane >> 4;
    const int wm = (w & 1) * 64, wn = (w >> 1) * 64;
    const int m0 = blockIdx.y * 128, n0 = blockIdx.x * 128;
    const int r4 = lane >> 2, c8 = (lane & 3) * 8;
    const short* ga = A + (size_t)(m0 + w * 16 + r4) * K + c8;
    const short* gb = Bt + (size_t)(n0 + w * 16 + r4) * K + c8;
    short* lA = As + (w * 16) * 32;   // wave-uniform LDS base, dst = base + lane*16B
    short* lB = Bs + (w * 16) * 32;

    float4v acc[4][4] = {};

    for (int k0 = 0; k0 < K; k0 += 32) {
        gl16(ga + k0, lA);
        gl16(ga + (size_t)64 * K + k0, lA + 64 * 32);
        gl16(gb + k0, lB);
        gl16(gb + (size_t)64 * K + k0, lB + 64 * 32);
        __syncthreads();   // drains vmcnt -> staging visible
        short8 af[4], bfr[4];
#pragma unroll
        for (int i = 0; i < 4; ++i)
            af[i] = *(const short8*)(As + (wm + i * 16 + l15) * 32 + quad * 8);
#pragma unroll
        for (int j = 0; j < 4; ++j)
            bfr[j] = *(const short8*)(Bs + (wn + j * 16 + l15) * 32 + quad * 8);
#pragma unroll
        for (int i = 0; i < 4; ++i)
#pragma unroll
            for (int j = 0; j < 4; ++j)
                acc[i][j] = __builtin_amdgcn_mfma_f32_16x16x32_bf16(af[i], bfr[j], acc[i][j], 0, 0, 0);
        __syncthreads();   // all reads done before next staging overwrite
    }

#pragma unroll
    for (int i = 0; i < 4; ++i) {
#pragma unroll
        for (int j = 0; j < 4; ++j) {
            const int col = n0 + wn + j * 16 + l15;
            const int row0 = m0 + wm + i * 16 + quad * 4;
            if (mode == 1) {
                const float bc = b0[col];
#pragma unroll
                for (int r = 0; r < 4; ++r)
                    Of[(size_t)(row0 + r) * 2048 + col] = acc[i][j][r] + bc;
            } else if (col < 2048) {
                const float bc = b0[col];
#pragma unroll
                for (int r = 0; r < 4; ++r)
                    O0[(size_t)(row0 + r) * 2048 + col] = f2bf(acc[i][j][r] + bc);
            } else if (col < 2560) {
                const int c = col - 2048;
                const float bc = b1[c];
#pragma unroll
                for (int r = 0; r < 4; ++r)
                    O1[(size_t)(row0 + r) * 512 + c] = f2bf(acc[i][j][r] + bc);
            } else {
                const int c = col - 2560;
                const float bc = b2[c];
                // token permutation for flash PV slot order: swap bits 2<->3 of the
                // within-16 token index (quad*4+r -> qsw*4+r)
                const int qsw = ((quad & 1) << 1) | (quad >> 1);
                const int prow = m0 + wm + i * 16 + qsw * 4;
#pragma unroll
                for (int r = 0; r < 4; ++r)
                    O2[(size_t)c * 4096 + prow + r] = f2bf(acc[i][j][r] + bc);
            }
        }
    }
}

// ---------------- Flash attention, 32x32 MFMA, in-register softmax ----------------
// grid (S/32, G, B), 256 threads = 4 waves. Wave w: head = g + 4*w (jnp.tile
// semantics: group = h % 4), q-rows = qt*32 .. +32 (shared by all 4 waves).
// Swapped QK^T: st = mfma(Kfrag, Qfrag) -> st[reg] = S[key, q=lane&31] with
// key = (reg&3)+8*(reg>>2)+4*(lane>>5) (+32 for st1). Softmax in-register.
// PV A-frag: straight bf16 pack of st regs; k-slot order matches V because Vt
// was token-permuted (bits 2<->3) at the QKV gemm epilogue.
// K/V double-buffered in LDS: ONE barrier per tile; loads prefetched 2 tiles deep.
// Mask fast-path: uniform branch skips per-key bit tests when tile unmasked.
// Half pipeline: softmax(st1) VALU runs under PV(st0) MFMAs.
__global__ __launch_bounds__(256, 2) void flash_kernel(
    const short* __restrict__ Qb, const short* __restrict__ Kb,
    const short* __restrict__ Vt, const int* __restrict__ mask,
    short* __restrict__ Ab) {
    __shared__ short Ks[2][64 * 136];   // keys x d, stride pad 136
    __shared__ short Vs[2][128 * 72];   // d x key-slot, stride pad 72

    const int t = threadIdx.x;
    const int lane = t & 63, w = t >> 6;            // w in 0..3
    const int l31 = lane & 31, hi = lane >> 5;
    const int qt = blockIdx.x, g = blockIdx.y, b = blockIdx.z;
    const int h = g + 4 * w;
    const int q0 = qt * 32;

    // Q fragments (B-operand of 32x32x16): lane: q-row = l31, d = dd*16 + hi*8 + j
    short8 qf[8];
#pragma unroll
    for (int dd = 0; dd < 8; ++dd)
        qf[dd] = *(const short8*)(Qb + (size_t)(b * 2048 + q0 + l31) * 2048
                                  + h * 128 + dd * 16 + hi * 8);

    float16v o[4] = {};
    float rsum = 0.f;

    const int kR = t >> 4, kC = (t & 15) * 8;  // K stage: rows kR+{0,16,32,48}
    const int vR = t >> 3, vC = (t & 7) * 8;   // V stage: rows vR+{0,32,64,96}
    const short* kg = Kb + (size_t)(b * 2048 + kR) * 512 + g * 128 + kC;
    const short* vg = Vt + (size_t)(g * 128 + vR) * 4096 + (size_t)b * 2048 + vC;

    short8 kv[4], vv[4];
    int mvr = 1;

#define LOADT(KB)                                                                  \
    do {                                                                           \
        kv[0] = *(const short8*)(kg + (size_t)(KB) * 512);                         \
        kv[1] = *(const short8*)(kg + (size_t)((KB) + 16) * 512);                  \
        kv[2] = *(const short8*)(kg + (size_t)((KB) + 32) * 512);                  \
        kv[3] = *(const short8*)(kg + (size_t)((KB) + 48) * 512);                  \
        vv[0] = *(const short8*)(vg + (KB));                                       \
        vv[1] = *(const short8*)(vg + (size_t)32 * 4096 + (KB));                   \
        vv[2] = *(const short8*)(vg + (size_t)64 * 4096 + (KB));                   \
        vv[3] = *(const short8*)(vg + (size_t)96 * 4096 + (KB));                   \
        mvr = mask[b * 2048 + (KB) + lane];                                        \
    } while (0)

#define STAGE(BUF)                                                                 \
    do {                                                                           \
        _Pragma("unroll")                                                          \
        for (int i_ = 0; i_ < 4; ++i_)                                             \
            *(short8*)(&Ks[BUF][(kR + i_ * 16) * 136 + kC]) = kv[i_];              \
        _Pragma("unroll")                                                          \
        for (int i_ = 0; i_ < 4; ++i_)                                             \
            *(short8*)(&Vs[BUF][(vR + i_ * 32) * 72 + vC]) = vv[i_];               \
    } while (0)

    LOADT(0);
    STAGE(0);
    unsigned long long bits = __ballot(mvr != 0);
    LOADT(64);
    __syncthreads();   // buf0 visible

    int cur = 0;
    unsigned long long bits_next = bits;

    for (int kt = 0; kt < 32; ++kt) {
        if (kt + 1 < 32) {
            STAGE(cur ^ 1);                       // tile kt+1 (safe: buf^1 last read in kt-1)
            bits_next = __ballot(mvr != 0);       // tile kt+1 mask bits
            if (kt + 2 < 32) LOADT((kt + 2) * 64);// prefetch 2 tiles ahead
        }
        const short* Ksb = &Ks[cur][0];
        const short* Vsb = &Vs[cur][0];

        // S^T = K @ Q^T : st[reg] = S[key, q=l31]
        float16v st0 = {}, st1 = {};
        __builtin_amdgcn_s_setprio(1);
#pragma unroll
        for (int dd = 0; dd < 8; ++dd) {
            short8 kf0 = *(const short8*)(Ksb + l31 * 136 + dd * 16 + hi * 8);
            short8 kf1 = *(const short8*)(Ksb + (32 + l31) * 136 + dd * 16 + hi * 8);
            st0 = __builtin_amdgcn_mfma_f32_32x32x16_bf16(kf0, qf[dd], st0, 0, 0, 0);
            st1 = __builtin_amdgcn_mfma_f32_32x32x16_bf16(kf1, qf[dd], st1, 0, 0, 0);
        }
        __builtin_amdgcn_s_setprio(0);

        const bool full = (bits == ~0ull);
        const unsigned int mlo = ((unsigned int)bits) >> (4 * hi);
        const unsigned int mhi = ((unsigned int)(bits >> 32)) >> (4 * hi);

        // softmax half 0 (st0): p = 2^(s*C1 + B0F)
        if (full) {
#pragma unroll
            for (int e = 0; e < 16; ++e) {
                float p0 = EXP2(fmaf(st0[e], C1F, B0F));
                rsum += p0; st0[e] = p0;
            }
        } else {
#pragma unroll
            for (int e = 0; e < 16; ++e) {
                const int koff = (e & 3) + 8 * (e >> 2);
                float p0 = EXP2(fmaf(st0[e], C1F, B0F));
                p0 = ((mlo >> koff) & 1) ? p0 : 0.f;
                rsum += p0; st0[e] = p0;
            }
        }

        // PV half 0 (cc=0,1): MFMAs issue, then softmax half 1 VALU runs underneath
        __builtin_amdgcn_s_setprio(1);
#pragma unroll
        for (int cc = 0; cc < 2; ++cc) {
            short8 pa;
#pragma unroll
            for (int e = 0; e < 8; ++e) pa[e] = f2bf(st0[cc * 8 + e]);
#pragma unroll
            for (int db = 0; db < 4; ++db) {
                short8 vb = *(const short8*)(Vsb + (db * 32 + l31) * 72 + cc * 16 + hi * 8);
                o[db] = __builtin_amdgcn_mfma_f32_32x32x16_bf16(pa, vb, o[db], 0, 0, 0);
            }
        }
        __builtin_amdgcn_s_setprio(0);

        // softmax half 1 (st1) — overlaps PV half 0 on the MFMA pipe
        if (full) {
#pragma unroll
            for (int e = 0; e < 16; ++e) {
                float p1 = EXP2(fmaf(st1[e], C1F, B0F));
                rsum += p1; st1[e] = p1;
            }
        } else {
#pragma unroll
            for (int e = 0; e < 16; ++e) {
                const int koff = (e & 3) + 8 * (e >> 2);
                float p1 = EXP2(fmaf(st1[e], C1F, B0F));
                p1 = ((mhi >> koff) & 1) ? p1 : 0.f;
                rsum += p1; st1[e] = p1;
            }
        }

        // PV half 1 (cc=2,3)
        __builtin_amdgcn_s_setprio(1);
#pragma unroll
        for (int cc = 2; cc < 4; ++cc) {
            short8 pa;
#pragma unroll
            for (int e = 0; e < 8; ++e) pa[e] = f2bf(st1[(cc & 1) * 8 + e]);
#pragma unroll
            for (int db = 0; db < 4; ++db) {
                short8 vb = *(const short8*)(Vsb + (db * 32 + l31) * 72 + cc * 16 + hi * 8);
                o[db] = __builtin_amdgcn_mfma_f32_32x32x16_bf16(pa, vb, o[db], 0, 0, 0);
            }
        }
        __builtin_amdgcn_s_setprio(0);

        __syncthreads();   // all waves done reading buf[cur]; kt+1 staging complete
        bits = bits_next;
        cur ^= 1;
    }
#undef LOADT
#undef STAGE

    // rsum: lane holds sum over its 32 keys for q=l31; partner (lane^32) has the rest
    rsum += __shfl_xor(rsum, 32, 64);
    const float rinv = (rsum > 0.f) ? 1.f / rsum : 0.f;
    // redistribute: store-time lane needs rinv of q-rows (reg&3)+8*(reg>>2)+4*hi
    float rq[16];
#pragma unroll
    for (int e = 0; e < 16; ++e) {
        const int koff = (e & 3) + 8 * (e >> 2);
        rq[e] = __shfl(rinv, koff + 4 * hi, 64);
    }
    const size_t ob = (size_t)(b * 2048 + q0) * 2048 + h * 128;
#pragma unroll
    for (int db = 0; db < 4; ++db)
#pragma unroll
        for (int e = 0; e < 16; ++e) {
            const int koff = (e & 3) + 8 * (e >> 2);
            Ab[ob + (size_t)(koff + 4 * hi) * 2048 + db * 32 + l31] =
                f2bf(o[db][e] * rq[e]);
        }
}

extern "C" void kernel_launch(void* const* d_in, const int* in_sizes, int n_in,
                              void* d_out, int out_size, void* d_ws, size_t ws_size,
                              hipStream_t stream) {
    (void)in_sizes; (void)n_in; (void)out_size; (void)ws_size;
    const float* X  = (const float*)d_in[0];
    const int* mask = (const int*)d_in[1];
    const float* Wq = (const float*)d_in[2];
    const float* bq = (const float*)d_in[3];
    const float* Wk = (const float*)d_in[4];
    const float* bk = (const float*)d_in[5];
    const float* Wv = (const float*)d_in[6];
    const float* bv = (const float*)d_in[7];
    const float* Wo = (const float*)d_in[8];
    const float* bo = (const float*)d_in[9];
    float* out = (float*)d_out;

    char* ws = (char*)d_ws;
    short* Xb     = (short*)(ws + 0);          // 16,777,216 B (reused as Ab)
    short* WqkvT  = (short*)(ws + 16777216);   // 12,582,912 B [3072,2048]
    short* Wot    = (short*)(ws + 29360128);   //  8,388,608 B
    short* Qb     = (short*)(ws + 37748736);   // 16,777,216 B
    short* Kb     = (short*)(ws + 54525952);   //  4,194,304 B
    short* Vt     = (short*)(ws + 58720256);   //  4,194,304 B
    short* Ab     = Xb;

    const int M = 4096, HID = 2048;

    cvt_bf16_kernel<<<8192, 256, 0, stream>>>(X, Xb, M * HID);
    transpose_all_kernel<<<dim3(160, 64), 256, 0, stream>>>(Wq, Wk, Wv, Wo, WqkvT, Wot);

    // fused Q|K|V projection: N = 3072
    gemm_dma_kernel<<<dim3(24, 32), 256, 0, stream>>>(
        Xb, WqkvT, bq, bk, bv, Qb, Kb, Vt, nullptr, HID, 0);

    flash_kernel<<<dim3(64, 4, 2), 256, 0, stream>>>(Qb, Kb, Vt, mask, Ab);

    gemm_dma_kernel<<<dim3(16, 32), 256, 0, stream>>>(
        Ab, Wot, bo, nullptr, nullptr, nullptr, nullptr, nullptr, out, HID, 1);
}